// Round 16
// baseline (126.595 us; speedup 1.0000x reference)
//
#include <hip/hip_runtime.h>
#include <math.h>

#define NN 5000      // nodes
#define NE 40000     // edges
#define UU 64        // hidden units
#define FE 16        // edge features
#define FEP 17       // +1 pseudo-feature for edge_bias
#define KD (FEP*UU)  // 1088
#define LDK (KD+8)   // padded LDS row (halfs); stride 548 dw == 4 mod 32
#define NSTEPS 4
#define NT 8         // nodes per step-tile (5000 % 8 == 0)
#define NB (NN/NT)   // 625 blocks
#define SLOT 40      // per-node edge bucket capacity (mean deg 8, P(>=40)~1e-15)
#define CH 8         // gather pipeline chunk
#define WBN (UU*KD)  // 69632
#define GTN (192*64) // 12288

typedef _Float16 half8 __attribute__((ext_vector_type(8)));
typedef float f32x4 __attribute__((ext_vector_type(4)));

__device__ __forceinline__ float sigm(float x){ return 1.f/(1.f + __expf(-x)); }
__device__ __forceinline__ int rfl(int x){ return __builtin_amdgcn_readfirstlane(x); }

// ---- build f16 weight tables + zero per-node degree counters ----
__global__ void build_k(const float* __restrict__ ek, const float* __restrict__ eb,
                        const float* __restrict__ gk, const float* __restrict__ rk,
                        _Float16* __restrict__ wb, _Float16* __restrict__ gkt,
                        _Float16* __restrict__ rkt, int* __restrict__ deg){
  int tid = blockIdx.x*blockDim.x + threadIdx.x;
  if (tid < NN) deg[tid] = 0;
  if (tid < WBN){
    int i = tid / KD, k = tid - i*KD;
    int f = k >> 6, j = k & 63;
    float v = (f < FE) ? ek[f*4096 + i*64 + j] : eb[i*64 + j];
    wb[tid] = (_Float16)v;
  } else if (tid < WBN + GTN){
    int r = tid - WBN; int n = r >> 6, k = r & 63;
    gkt[r] = (_Float16)gk[k*192 + n];
  } else if (tid < WBN + 2*GTN){
    int r = tid - WBN - GTN; int n = r >> 6, k = r & 63;
    rkt[r] = (_Float16)rk[k*192 + n];
  }
}

// ---- bucket edges by src (atomic slot alloc; order canonicalized in prep_k) ----
__global__ void bucket_k(const int* __restrict__ pair, int* __restrict__ deg,
                         int* __restrict__ eidb){
  int e = blockIdx.x*blockDim.x + threadIdx.x;
  if (e < NE){
    int v = pair[2*e];
    int pos = atomicAdd(&deg[v], 1);
    if (pos < SLOT) eidb[v*SLOT + pos] = e;
  }
}

// ---- canonical order via lane-parallel rank (edge ids unique) + resolve nbr ----
__global__ __launch_bounds__(512) void prep_k(const int* __restrict__ pair,
                       const int* __restrict__ deg,
                       const int* __restrict__ eidb, int2* __restrict__ enb){
  int w = threadIdx.x >> 6, lane = threadIdx.x & 63;
  int v = blockIdx.x * 8 + w;
  if (v >= NN) return;
  int dg = deg[v]; if (dg > SLOT) dg = SLOT;
  if (lane < dg){
    int e = eidb[v*SLOT + lane];
    int rank = 0;
    for (int j=0; j<dg; ++j){ int ej = eidb[v*SLOT + j]; rank += (ej < e); }
    enb[v*SLOT + rank] = make_int2(e, pair[2*e + 1]);
  }
}

// ---- fused step, 8-node tile, 4 waves (256 thr): gather 2 nodes/wave ->
// ---- all-wave MFMA agg (A rows 0-7) -> all-wave MFMA GRU ----
// 256-thr blocks: ~20 KB LDS -> up to 8 blocks/CU resident (vs 2.4 at 512 thr)
__global__ __launch_bounds__(256) void step_k(const float* __restrict__ h_in,
        float* __restrict__ h_out, const float* __restrict__ ef,
        const int* __restrict__ deg, const int2* __restrict__ enb,
        const _Float16* __restrict__ wb, const _Float16* __restrict__ gkt,
        const _Float16* __restrict__ rkt, const float* __restrict__ gb){
  __shared__ _Float16 Gs[NT*LDK];      // 17536 B
  __shared__ _Float16 aggT[NT*72];     // 1152 B
  __shared__ _Float16 hT[NT*72];       // 1152 B

  int tid = threadIdx.x;
  int w = tid >> 6, lane = tid & 63;
  int r16 = lane & 15, kh = lane >> 4;
  int vb = blockIdx.x * NT;

  // ---- gather: wave w owns nodes v0 = vb+2w, v1 = v0+1 (interleaved) ----
  {
    int v0 = vb + w*2, v1 = v0 + 1;
    hT[(w*2  )*72 + lane] = (_Float16)h_in[(size_t)v0*64 + lane];
    hT[(w*2+1)*72 + lane] = (_Float16)h_in[(size_t)v1*64 + lane];
    int d0 = rfl(deg[v0]); if (d0 > SLOT) d0 = SLOT;
    int d1 = rfl(deg[v1]); if (d1 > SLOT) d1 = SLOT;
    const int2* l0 = enb + (size_t)v0*SLOT;
    const int2* l1 = enb + (size_t)v1*SLOT;
    float gA[FEP], gB[FEP];
    #pragma unroll
    for (int f=0;f<FEP;++f){ gA[f] = 0.f; gB[f] = 0.f; }
    int dmax = (d0 > d1) ? d0 : d1;
    for (int c0=0; c0<dmax; c0+=CH){
      int eA[CH], nA[CH], eB[CH], nB[CH];
      #pragma unroll
      for (int q=0;q<CH;++q){ int i=c0+q;
        if (i<d0){ int2 p = l0[i]; eA[q]=rfl(p.x); nA[q]=rfl(p.y); }
        else { eA[q]=0; nA[q]=0; }
        if (i<d1){ int2 p = l1[i]; eB[q]=rfl(p.x); nB[q]=rfl(p.y); }
        else { eB[q]=0; nB[q]=0; } }
      float hA[CH], hB[CH];
      #pragma unroll
      for (int q=0;q<CH;++q){ int i=c0+q;
        hA[q] = (i<d0) ? h_in[(size_t)nA[q]*64 + lane] : 0.f;
        hB[q] = (i<d1) ? h_in[(size_t)nB[q]*64 + lane] : 0.f; }
      #pragma unroll
      for (int q=0;q<CH;++q){ int i=c0+q;
        if (i<d0){
          const float4* er = (const float4*)(ef + (size_t)eA[q]*FE);
          float4 e0 = er[0], e1 = er[1], e2 = er[2], e3 = er[3];
          float hj = hA[q];
          gA[ 0]=fmaf(e0.x,hj,gA[ 0]); gA[ 1]=fmaf(e0.y,hj,gA[ 1]);
          gA[ 2]=fmaf(e0.z,hj,gA[ 2]); gA[ 3]=fmaf(e0.w,hj,gA[ 3]);
          gA[ 4]=fmaf(e1.x,hj,gA[ 4]); gA[ 5]=fmaf(e1.y,hj,gA[ 5]);
          gA[ 6]=fmaf(e1.z,hj,gA[ 6]); gA[ 7]=fmaf(e1.w,hj,gA[ 7]);
          gA[ 8]=fmaf(e2.x,hj,gA[ 8]); gA[ 9]=fmaf(e2.y,hj,gA[ 9]);
          gA[10]=fmaf(e2.z,hj,gA[10]); gA[11]=fmaf(e2.w,hj,gA[11]);
          gA[12]=fmaf(e3.x,hj,gA[12]); gA[13]=fmaf(e3.y,hj,gA[13]);
          gA[14]=fmaf(e3.z,hj,gA[14]); gA[15]=fmaf(e3.w,hj,gA[15]);
          gA[16] += hj;
        }
        if (i<d1){
          const float4* er = (const float4*)(ef + (size_t)eB[q]*FE);
          float4 e0 = er[0], e1 = er[1], e2 = er[2], e3 = er[3];
          float hj = hB[q];
          gB[ 0]=fmaf(e0.x,hj,gB[ 0]); gB[ 1]=fmaf(e0.y,hj,gB[ 1]);
          gB[ 2]=fmaf(e0.z,hj,gB[ 2]); gB[ 3]=fmaf(e0.w,hj,gB[ 3]);
          gB[ 4]=fmaf(e1.x,hj,gB[ 4]); gB[ 5]=fmaf(e1.y,hj,gB[ 5]);
          gB[ 6]=fmaf(e1.z,hj,gB[ 6]); gB[ 7]=fmaf(e1.w,hj,gB[ 7]);
          gB[ 8]=fmaf(e2.x,hj,gB[ 8]); gB[ 9]=fmaf(e2.y,hj,gB[ 9]);
          gB[10]=fmaf(e2.z,hj,gB[10]); gB[11]=fmaf(e2.w,hj,gB[11]);
          gB[12]=fmaf(e3.x,hj,gB[12]); gB[13]=fmaf(e3.y,hj,gB[13]);
          gB[14]=fmaf(e3.z,hj,gB[14]); gB[15]=fmaf(e3.w,hj,gB[15]);
          gB[16] += hj;
        } }
    }
    #pragma unroll
    for (int f=0;f<FEP;++f){
      Gs[(w*2  )*LDK + f*64 + lane] = (_Float16)gA[f];
      Gs[(w*2+1)*LDK + f*64 + lane] = (_Float16)gB[f];
    }
  }
  __syncthreads();

  // ---- agg matmul: ALL 4 waves, wave w = cols w*16..w*16+15; A rows 0-7 ----
  {
    f32x4 acc = {0.f,0.f,0.f,0.f};
    const _Float16* ap = Gs + (r16 & 7)*LDK + kh*8;
    const _Float16* bp = wb + (size_t)(w*16 + r16)*KD + kh*8;
    #pragma unroll 4
    for (int k0=0; k0<KD; k0+=32){
      half8 a = *(const half8*)(ap + k0);
      half8 b = *(const half8*)(bp + k0);
      acc = __builtin_amdgcn_mfma_f32_16x16x32_f16(a, b, acc, 0, 0, 0);
    }
    if (kh < 2){           // C rows 0-7 live in kh 0,1 (row = kh*4+r)
      #pragma unroll
      for (int r=0;r<4;++r) aggT[(kh*4+r)*72 + w*16 + r16] = (_Float16)acc[r];
    }
  }
  __syncthreads();

  // ---- GRU via MFMA: ALL 4 waves, wave w owns units uw = w*16 + r16 ----
  {
    int uw = w*16 + r16;
    const _Float16* az = aggT + (r16 & 7)*72 + kh*8;
    const _Float16* ah = hT   + (r16 & 7)*72 + kh*8;
    f32x4 mxz={0.f,0.f,0.f,0.f}, mxr=mxz, mxh=mxz, mhz=mxz, mhr=mxz, mhh=mxz;
    #pragma unroll
    for (int ks=0; ks<2; ++ks){
      half8 aa = *(const half8*)(az + ks*32);
      half8 hh = *(const half8*)(ah + ks*32);
      half8 bz = *(const half8*)(gkt + (size_t)(      uw)*64 + ks*32 + kh*8);
      half8 br = *(const half8*)(gkt + (size_t)( 64 + uw)*64 + ks*32 + kh*8);
      half8 bh = *(const half8*)(gkt + (size_t)(128 + uw)*64 + ks*32 + kh*8);
      half8 cz = *(const half8*)(rkt + (size_t)(      uw)*64 + ks*32 + kh*8);
      half8 cr = *(const half8*)(rkt + (size_t)( 64 + uw)*64 + ks*32 + kh*8);
      half8 ch = *(const half8*)(rkt + (size_t)(128 + uw)*64 + ks*32 + kh*8);
      mxz = __builtin_amdgcn_mfma_f32_16x16x32_f16(aa, bz, mxz, 0,0,0);
      mxr = __builtin_amdgcn_mfma_f32_16x16x32_f16(aa, br, mxr, 0,0,0);
      mxh = __builtin_amdgcn_mfma_f32_16x16x32_f16(aa, bh, mxh, 0,0,0);
      mhz = __builtin_amdgcn_mfma_f32_16x16x32_f16(hh, cz, mhz, 0,0,0);
      mhr = __builtin_amdgcn_mfma_f32_16x16x32_f16(hh, cr, mhr, 0,0,0);
      mhh = __builtin_amdgcn_mfma_f32_16x16x32_f16(hh, ch, mhh, 0,0,0);
    }
    if (kh < 2){
      float b0z = gb[uw],      b0r = gb[64+uw],  b0h = gb[128+uw];
      float b1z = gb[192+uw],  b1r = gb[256+uw], b1h = gb[320+uw];
      #pragma unroll
      for (int r=0;r<4;++r){
        int row = vb + kh*4 + r;
        float z  = sigm(mxz[r] + b0z + mhz[r] + b1z);
        float rr = sigm(mxr[r] + b0r + mhr[r] + b1r);
        float hc = tanhf(mxh[r] + b0h + rr*(mhh[r] + b1h));
        float hold = h_in[(size_t)row*64 + uw];
        h_out[(size_t)row*64 + uw] = z*hold + (1.f - z)*hc;
      }
    }
  }
}

extern "C" void kernel_launch(void* const* d_in, const int* in_sizes, int n_in,
                              void* d_out, int out_size, void* d_ws, size_t ws_size,
                              hipStream_t stream){
  const float* nodef = (const float*)d_in[0];
  const float* edgef = (const float*)d_in[1];
  const int*   pair  = (const int*)  d_in[2];
  const float* ek    = (const float*)d_in[3];
  const float* ebias = (const float*)d_in[4];
  const float* gk    = (const float*)d_in[5];
  const float* rk    = (const float*)d_in[6];
  const float* gb    = (const float*)d_in[7];

  char* ws = (char*)d_ws;
  size_t o = 0;
  auto carve = [&](size_t bytes)->char*{
    char* p = ws + o; o = (o + bytes + 255) & ~255ULL; return p; };
  int*      deg  = (int*)     carve(NN*sizeof(int));
  int*      eidb = (int*)     carve((size_t)NN*SLOT*sizeof(int));
  int2*     enb  = (int2*)    carve((size_t)NN*SLOT*sizeof(int2));
  _Float16* wb   = (_Float16*)carve((size_t)WBN*sizeof(_Float16));
  _Float16* gkt  = (_Float16*)carve((size_t)GTN*sizeof(_Float16));
  _Float16* rkt  = (_Float16*)carve((size_t)GTN*sizeof(_Float16));
  float*    hA   = (float*)   carve((size_t)NN*UU*sizeof(float));
  float*    hB   = (float*)   carve((size_t)NN*UU*sizeof(float));

  build_k <<<(WBN+2*GTN+255)/256, 256, 0, stream>>>(ek, ebias, gk, rk, wb, gkt, rkt, deg);
  bucket_k<<<(NE+255)/256, 256, 0, stream>>>(pair, deg, eidb);
  prep_k  <<<NB, 512, 0, stream>>>(pair, deg, eidb, enb);

  const float* hin = nodef;
  for (int s=0; s<NSTEPS; ++s){
    float* hout = (s == NSTEPS-1) ? (float*)d_out : ((s & 1) ? hB : hA);
    step_k<<<NB, 256, 0, stream>>>(hin, hout, edgef, deg, enb,
                                   wb, gkt, rkt, gb);
    hin = hout;
  }
}

// Round 17
// 114.723 us; speedup vs baseline: 1.1035x; 1.1035x over previous
//
#include <hip/hip_runtime.h>
#include <math.h>

#define NN 5000      // nodes
#define NE 40000     // edges
#define UU 64        // hidden units
#define FE 16        // edge features
#define FEP 17       // +1 pseudo-feature for edge_bias
#define KD (FEP*UU)  // 1088
#define LDK (KD+8)   // padded LDS row (halfs); stride 548 dw == 4 mod 32
#define NSTEPS 4
#define NT 8         // nodes per step-tile (5000 % 8 == 0)
#define NB (NN/NT)   // 625 blocks
#define SLOT 40      // per-node edge bucket capacity (mean deg 8, P(>=40)~1e-15)
#define CH 8         // gather pipeline chunk
#define WBN (UU*KD)  // 69632
#define GTN (192*64) // 12288

typedef _Float16 half8 __attribute__((ext_vector_type(8)));
typedef float f32x4 __attribute__((ext_vector_type(4)));

__device__ __forceinline__ float sigm(float x){ return 1.f/(1.f + __expf(-x)); }
__device__ __forceinline__ int rfl(int x){ return __builtin_amdgcn_readfirstlane(x); }

// ---- build f16 weight tables + zero per-node degree counters ----
__global__ void build_k(const float* __restrict__ ek, const float* __restrict__ eb,
                        const float* __restrict__ gk, const float* __restrict__ rk,
                        _Float16* __restrict__ wb, _Float16* __restrict__ gkt,
                        _Float16* __restrict__ rkt, int* __restrict__ deg){
  int tid = blockIdx.x*blockDim.x + threadIdx.x;
  if (tid < NN) deg[tid] = 0;
  if (tid < WBN){
    int i = tid / KD, k = tid - i*KD;
    int f = k >> 6, j = k & 63;
    float v = (f < FE) ? ek[f*4096 + i*64 + j] : eb[i*64 + j];
    wb[tid] = (_Float16)v;
  } else if (tid < WBN + GTN){
    int r = tid - WBN; int n = r >> 6, k = r & 63;
    gkt[r] = (_Float16)gk[k*192 + n];
  } else if (tid < WBN + 2*GTN){
    int r = tid - WBN - GTN; int n = r >> 6, k = r & 63;
    rkt[r] = (_Float16)rk[k*192 + n];
  }
}

// ---- bucket edges by src (atomic slot alloc; order canonicalized in prep_k) ----
__global__ void bucket_k(const int* __restrict__ pair, int* __restrict__ deg,
                         int* __restrict__ eidb){
  int e = blockIdx.x*blockDim.x + threadIdx.x;
  if (e < NE){
    int v = pair[2*e];
    int pos = atomicAdd(&deg[v], 1);
    if (pos < SLOT) eidb[v*SLOT + pos] = e;
  }
}

// ---- canonical order via lane-parallel rank (edge ids unique) + resolve nbr ----
__global__ __launch_bounds__(512) void prep_k(const int* __restrict__ pair,
                       const int* __restrict__ deg,
                       const int* __restrict__ eidb, int2* __restrict__ enb){
  int w = threadIdx.x >> 6, lane = threadIdx.x & 63;
  int v = blockIdx.x * 8 + w;
  if (v >= NN) return;
  int dg = deg[v]; if (dg > SLOT) dg = SLOT;
  if (lane < dg){
    int e = eidb[v*SLOT + lane];
    int rank = 0;
    for (int j=0; j<dg; ++j){ int ej = eidb[v*SLOT + j]; rank += (ej < e); }
    enb[v*SLOT + rank] = make_int2(e, pair[2*e + 1]);
  }
}

// ---- fused step, 8-node tile, 8 waves: gather (1 wave/node) -> MFMA agg -> MFMA GRU ----
__global__ __launch_bounds__(512) void step_k(const float* __restrict__ h_in,
        float* __restrict__ h_out, const float* __restrict__ ef,
        const int* __restrict__ deg, const int2* __restrict__ enb,
        const _Float16* __restrict__ wb, const _Float16* __restrict__ gkt,
        const _Float16* __restrict__ rkt, const float* __restrict__ gb){
  __shared__ _Float16 Gs[NT*LDK];      // 17536 B
  __shared__ _Float16 aggT[NT*72];     // 1152 B
  __shared__ _Float16 hT[NT*72];       // 1152 B

  int tid = threadIdx.x;
  int w = tid >> 6, lane = tid & 63;
  int r16 = lane & 15, kh = lane >> 4;
  int vb = blockIdx.x * NT;
  int v  = vb + w;                     // this wave's node

  hT[w*72 + lane] = (_Float16)h_in[(size_t)v*64 + lane];

  // ---- gather: wave w owns node v (17 features, lane = unit) ----
  {
    int dgv = rfl(deg[v]); if (dgv > SLOT) dgv = SLOT;
    const int2* lst = enb + v*SLOT;
    float g[FEP];
    #pragma unroll
    for (int f=0;f<FEP;++f) g[f] = 0.f;
    for (int c0=0; c0<dgv; c0+=CH){
      int ee[CH], nb[CH];
      #pragma unroll
      for (int q=0;q<CH;++q){ int i=c0+q;
        if (i<dgv){ int2 p = lst[i]; ee[q]=rfl(p.x); nb[q]=rfl(p.y); }
        else { ee[q]=0; nb[q]=0; } }
      float hj[CH];
      #pragma unroll
      for (int q=0;q<CH;++q){ int i=c0+q;
        hj[q] = (i<dgv) ? h_in[(size_t)nb[q]*64 + lane] : 0.f; }
      #pragma unroll
      for (int q=0;q<CH;++q){ int i=c0+q;
        if (i<dgv){
          const float4* er = (const float4*)(ef + (size_t)ee[q]*FE);
          float4 e0 = er[0], e1 = er[1], e2 = er[2], e3 = er[3];
          g[ 0]=fmaf(e0.x,hj[q],g[ 0]); g[ 1]=fmaf(e0.y,hj[q],g[ 1]);
          g[ 2]=fmaf(e0.z,hj[q],g[ 2]); g[ 3]=fmaf(e0.w,hj[q],g[ 3]);
          g[ 4]=fmaf(e1.x,hj[q],g[ 4]); g[ 5]=fmaf(e1.y,hj[q],g[ 5]);
          g[ 6]=fmaf(e1.z,hj[q],g[ 6]); g[ 7]=fmaf(e1.w,hj[q],g[ 7]);
          g[ 8]=fmaf(e2.x,hj[q],g[ 8]); g[ 9]=fmaf(e2.y,hj[q],g[ 9]);
          g[10]=fmaf(e2.z,hj[q],g[10]); g[11]=fmaf(e2.w,hj[q],g[11]);
          g[12]=fmaf(e3.x,hj[q],g[12]); g[13]=fmaf(e3.y,hj[q],g[13]);
          g[14]=fmaf(e3.z,hj[q],g[14]); g[15]=fmaf(e3.w,hj[q],g[15]);
          g[16] += hj[q];
        } }
    }
    #pragma unroll
    for (int f=0;f<FEP;++f) Gs[w*LDK + f*64 + lane] = (_Float16)g[f];
  }
  __syncthreads();

  // ---- agg matmul: waves 0-3, wave w = cols w*16..w*16+15; A rows 0-7 valid ----
  if (w < 4){
    f32x4 acc = {0.f,0.f,0.f,0.f};
    const _Float16* ap = Gs + (r16 & 7)*LDK + kh*8;
    const _Float16* bp = wb + (size_t)(w*16 + r16)*KD + kh*8;
    #pragma unroll 4
    for (int k0=0; k0<KD; k0+=32){
      half8 a = *(const half8*)(ap + k0);
      half8 b = *(const half8*)(bp + k0);
      acc = __builtin_amdgcn_mfma_f32_16x16x32_f16(a, b, acc, 0, 0, 0);
    }
    if (kh < 2){           // C rows 0-7 live in kh 0,1 (row = kh*4+r)
      #pragma unroll
      for (int r=0;r<4;++r) aggT[(kh*4+r)*72 + w*16 + r16] = (_Float16)acc[r];
    }
  }
  __syncthreads();

  // ---- GRU via MFMA: waves 0-3, wave w owns units uw = w*16 + r16 ----
  if (w < 4){
    int uw = w*16 + r16;
    const _Float16* az = aggT + (r16 & 7)*72 + kh*8;
    const _Float16* ah = hT   + (r16 & 7)*72 + kh*8;
    f32x4 mxz={0.f,0.f,0.f,0.f}, mxr=mxz, mxh=mxz, mhz=mxz, mhr=mxz, mhh=mxz;
    #pragma unroll
    for (int ks=0; ks<2; ++ks){
      half8 aa = *(const half8*)(az + ks*32);
      half8 hh = *(const half8*)(ah + ks*32);
      half8 bz = *(const half8*)(gkt + (size_t)(      uw)*64 + ks*32 + kh*8);
      half8 br = *(const half8*)(gkt + (size_t)( 64 + uw)*64 + ks*32 + kh*8);
      half8 bh = *(const half8*)(gkt + (size_t)(128 + uw)*64 + ks*32 + kh*8);
      half8 cz = *(const half8*)(rkt + (size_t)(      uw)*64 + ks*32 + kh*8);
      half8 cr = *(const half8*)(rkt + (size_t)( 64 + uw)*64 + ks*32 + kh*8);
      half8 ch = *(const half8*)(rkt + (size_t)(128 + uw)*64 + ks*32 + kh*8);
      mxz = __builtin_amdgcn_mfma_f32_16x16x32_f16(aa, bz, mxz, 0,0,0);
      mxr = __builtin_amdgcn_mfma_f32_16x16x32_f16(aa, br, mxr, 0,0,0);
      mxh = __builtin_amdgcn_mfma_f32_16x16x32_f16(aa, bh, mxh, 0,0,0);
      mhz = __builtin_amdgcn_mfma_f32_16x16x32_f16(hh, cz, mhz, 0,0,0);
      mhr = __builtin_amdgcn_mfma_f32_16x16x32_f16(hh, cr, mhr, 0,0,0);
      mhh = __builtin_amdgcn_mfma_f32_16x16x32_f16(hh, ch, mhh, 0,0,0);
    }
    if (kh < 2){
      float b0z = gb[uw],      b0r = gb[64+uw],  b0h = gb[128+uw];
      float b1z = gb[192+uw],  b1r = gb[256+uw], b1h = gb[320+uw];
      #pragma unroll
      for (int r=0;r<4;++r){
        int row = vb + kh*4 + r;
        float z  = sigm(mxz[r] + b0z + mhz[r] + b1z);
        float rr = sigm(mxr[r] + b0r + mhr[r] + b1r);
        float hc = tanhf(mxh[r] + b0h + rr*(mhh[r] + b1h));
        float hold = h_in[(size_t)row*64 + uw];
        h_out[(size_t)row*64 + uw] = z*hold + (1.f - z)*hc;
      }
    }
  }
}

extern "C" void kernel_launch(void* const* d_in, const int* in_sizes, int n_in,
                              void* d_out, int out_size, void* d_ws, size_t ws_size,
                              hipStream_t stream){
  const float* nodef = (const float*)d_in[0];
  const float* edgef = (const float*)d_in[1];
  const int*   pair  = (const int*)  d_in[2];
  const float* ek    = (const float*)d_in[3];
  const float* ebias = (const float*)d_in[4];
  const float* gk    = (const float*)d_in[5];
  const float* rk    = (const float*)d_in[6];
  const float* gb    = (const float*)d_in[7];

  char* ws = (char*)d_ws;
  size_t o = 0;
  auto carve = [&](size_t bytes)->char*{
    char* p = ws + o; o = (o + bytes + 255) & ~255ULL; return p; };
  int*      deg  = (int*)     carve(NN*sizeof(int));
  int*      eidb = (int*)     carve((size_t)NN*SLOT*sizeof(int));
  int2*     enb  = (int2*)    carve((size_t)NN*SLOT*sizeof(int2));
  _Float16* wb   = (_Float16*)carve((size_t)WBN*sizeof(_Float16));
  _Float16* gkt  = (_Float16*)carve((size_t)GTN*sizeof(_Float16));
  _Float16* rkt  = (_Float16*)carve((size_t)GTN*sizeof(_Float16));
  float*    hA   = (float*)   carve((size_t)NN*UU*sizeof(float));
  float*    hB   = (float*)   carve((size_t)NN*UU*sizeof(float));

  build_k <<<(WBN+2*GTN+255)/256, 256, 0, stream>>>(ek, ebias, gk, rk, wb, gkt, rkt, deg);
  bucket_k<<<(NE+255)/256, 256, 0, stream>>>(pair, deg, eidb);
  prep_k  <<<NB, 512, 0, stream>>>(pair, deg, eidb, enb);

  const float* hin = nodef;
  for (int s=0; s<NSTEPS; ++s){
    float* hout = (s == NSTEPS-1) ? (float*)d_out : ((s & 1) ? hB : hA);
    step_k<<<NB, 512, 0, stream>>>(hin, hout, edgef, deg, enb,
                                   wb, gkt, rkt, gb);
    hin = hout;
  }
}